// Round 11
// baseline (1284.056 us; speedup 1.0000x reference)
//
#include <hip/hip_runtime.h>
#include <hip/hip_bf16.h>

// Problem constants
#define BB    4
#define CIN_  64
#define RIN_  6
#define CH_   5
#define HH    64
#define WW_   128
#define KD    384
#define MD    384
#define PH    66
#define PW    130
#define PSZ   (PH*PW)

#define NTAP 7
#define WEXP2_ELEMS (NTAP*MD*KD)
#define WEXP2_BYTES (WEXP2_ELEMS*2)
#define NBORD 388

typedef __hip_bfloat16 bf16;
typedef __attribute__((ext_vector_type(8))) short bf16x8;
typedef __attribute__((ext_vector_type(4))) float f32x4;

__device__ const int TMAP[NTAP] = {0,1,3,4,5,7,8};
__device__ const int IDXK[6][9] = {
    {5,4,6,6,0,3,6,1,2},
    {4,3,6,5,0,2,6,6,1},
    {3,2,6,4,0,1,6,5,6},
    {2,1,6,3,0,6,6,4,5},
    {1,6,6,2,0,5,6,3,4},
    {6,5,6,1,0,4,6,2,3},
};

// -------- kernel 1: expand weight -> W2 bf16 [tt=7][m=384][k=384]
__global__ void wexp2_kernel(const float* __restrict__ w, bf16* __restrict__ W2) {
    int e = blockIdx.x * blockDim.x + threadIdx.x;
    if (e >= WEXP2_ELEMS) return;
    int k  = e % KD;
    int m  = (e / KD) % MD;
    int tt = e / (KD * MD);
    int t  = TMAP[tt];
    int co = m / 6, ro = m % 6, ci = k / 6, ri = k % 6;
    int rw = (ri - ro + 6) % 6;
    int s  = IDXK[ro][t];
    W2[e] = __float2bfloat16(w[((co * CIN_ + ci) * RIN_ + rw) * 7 + s]);
}

// -------- kernel 2a: interior pad (transpose to channel-last)
// P layout: [b][c][yy=66][xx=130][k=384] bf16
__global__ __launch_bounds__(256) void pad_interior(const float* __restrict__ x,
                                                    bf16* __restrict__ P) {
    int bid  = blockIdx.x;
    int kblk = bid % 3;
    int xh   = (bid / 3) & 1;
    int y    = (bid / 6) % 64;
    int bc   = bid / 384;
    int c = bc % 5, b = bc / 5;

    int lane = threadIdx.x & 63;
    int wv   = threadIdx.x >> 6;
    int k0   = kblk * 128 + wv * 32;
    int sx   = xh * 64 + lane;
    int xx   = sx + 1;

    bool mask0 = (y == 0 && sx == 127) || (y == 63 && sx == 0);

    const float* src = x + ((((size_t)(b * 384 + k0) * 5 + c) * 64 + y) * 128 + sx);
    unsigned int hbuf[16];
    #pragma unroll
    for (int kk = 0; kk < 32; kk += 2) {
        float v1 = src[(size_t)kk * 40960];
        float v2 = src[(size_t)(kk + 1) * 40960];
        if (mask0) { v1 = 0.f; v2 = 0.f; }
        bf16 h1 = __float2bfloat16(v1);
        bf16 h2 = __float2bfloat16(v2);
        hbuf[kk >> 1] = ((unsigned int)*(unsigned short*)&h2 << 16) |
                        (unsigned int)*(unsigned short*)&h1;
    }
    bf16* dst = P + (((size_t)(b * 5 + c) * PH + (y + 1)) * PW + xx) * KD + k0;
    uint4* d4 = (uint4*)dst;
    #pragma unroll
    for (int q = 0; q < 4; ++q)
        d4[q] = make_uint4(hbuf[4*q], hbuf[4*q+1], hbuf[4*q+2], hbuf[4*q+3]);
}

// -------- kernel 2b: border gather
__global__ void pad_border(const float* __restrict__ x, bf16* __restrict__ P) {
    int e = blockIdx.x * blockDim.x + threadIdx.x;
    if (e >= 20 * NBORD * KD) return;
    int k  = e % KD;
    int p  = (e / KD) % NBORD;
    int bc = e / (KD * NBORD);
    int c = bc % 5, b = bc / 5;
    int yy, xx;
    if (p < 130)      { yy = 0;  xx = p; }
    else if (p < 260) { yy = 65; xx = p - 130; }
    else if (p < 324) { yy = 1 + (p - 260); xx = 0; }
    else              { yy = 1 + (p - 324); xx = 129; }

    int ci = k / RIN_, r = k % RIN_;
    int sr = r, sc = c, sy = 0, sx = 0;
    bool zi = false;
    if (xx == 129) {
        if (yy >= 2) { sr = (r + 5) % 6; sc = (c + 1) % 5; sy = 0; sx = 129 - yy; }
        else zi = true;
    } else if (yy == 0) {
        if (xx >= 1 && xx <= 64)        { sc = (c + 4) % 5; sy = 63; sx = 63 + xx; }
        else if (xx >= 65 && xx <= 128) { sr = (r + 1) % 6; sc = (c + 4) % 5; sy = 128 - xx; sx = 127; }
        else zi = true;
    } else if (yy == 65) {
        if (xx >= 65 && xx <= 128)      { sc = (c + 1) % 5; sy = 0; sx = xx - 65; }
        else if (xx >= 2 && xx <= 64)   { sr = (r + 1) % 6; sc = (c + 1) % 5; sy = 65 - xx; sx = 0; }
        else zi = true;
    } else { // xx==0, yy in [1,64]
        sr = (r + 5) % 6; sc = (c + 4) % 5; sy = 63; sx = 64 - yy;
    }
    if (zi) { sr = 0; sc = 0; sy = 0; sx = 0; }
    float v = x[((((size_t)b * 384 + (ci * 6 + sr)) * 5 + sc) * 64 + sy) * 128 + sx];
    if ((sy == 0 && sx == 127) || (sy == 63 && sx == 0)) v = 0.f;
    P[(((size_t)(b * 5 + c) * PH + yy) * PW + xx) * KD + k] = __float2bfloat16(v);
}

// -------- kernel 3: implicit-GEMM conv, strip-staged B + register A
// 4 waves/block (256 thr); wave-tile 128m x 64n (acc 8x4 frags), BM=128, BN=256.
// K loop: chunk-outer (12 x BK=32), tap-inner (7). Per chunk: stage 4-row x 132-col
// B strip ONCE (9 GLD/wave); A fragments loaded global->reg (L2-hot W2),
// double-generation, issued one tap ahead. ONE barrier per chunk (12 total),
// counted vmcnt(8) at chunk edges only; no mid-chunk manual waits.
#define GLD(g, l) __builtin_amdgcn_global_load_lds( \
    (const __attribute__((address_space(1))) void*)(g), \
    (__attribute__((address_space(3))) void*)(l), 16, 0, 0)
#define MFMA_(a, b, c) __builtin_amdgcn_mfma_f32_16x16x32_bf16((a), (b), (c), 0, 0, 0)

// one tap iteration; J, DYv, DXv, SB are literal constants at each expansion
#define BODY(KC, J, DYv, DXv, SB, AC, AN, LAST_IT) {                              \
    if (!(LAST_IT)) {   /* A prefetch for next tap (8 x dwordx4, reg dest) */     \
        const int ntt = ((J) + 1) % 7;                                            \
        const int nkc = (KC) + ((J) + 1) / 7;                                     \
        const bf16* ap = gAbase + (size_t)ntt * (MD * KD) + nkc * 32;             \
        AN[0] = *(const bf16x8*)(ap + 0 * (16 * KD));                             \
        AN[1] = *(const bf16x8*)(ap + 1 * (16 * KD));                             \
        AN[2] = *(const bf16x8*)(ap + 2 * (16 * KD));                             \
        AN[3] = *(const bf16x8*)(ap + 3 * (16 * KD));                             \
        AN[4] = *(const bf16x8*)(ap + 4 * (16 * KD));                             \
        AN[5] = *(const bf16x8*)(ap + 5 * (16 * KD));                             \
        AN[6] = *(const bf16x8*)(ap + 6 * (16 * KD));                             \
        AN[7] = *(const bf16x8*)(ap + 7 * (16 * KD));                             \
    }                                                                             \
    if ((J) == 0 && (KC) < 11) {  /* stage next chunk's strip (after A issue) */  \
        const int ko = ((KC) + 1) * 64;                                           \
        GLD(Pbyte + so[0] + ko, &Ss[((KC) + 1) & 1][(wv * 528 + 0 * 64) * 8]);    \
        GLD(Pbyte + so[1] + ko, &Ss[((KC) + 1) & 1][(wv * 528 + 1 * 64) * 8]);    \
        GLD(Pbyte + so[2] + ko, &Ss[((KC) + 1) & 1][(wv * 528 + 2 * 64) * 8]);    \
        GLD(Pbyte + so[3] + ko, &Ss[((KC) + 1) & 1][(wv * 528 + 3 * 64) * 8]);    \
        GLD(Pbyte + so[4] + ko, &Ss[((KC) + 1) & 1][(wv * 528 + 4 * 64) * 8]);    \
        GLD(Pbyte + so[5] + ko, &Ss[((KC) + 1) & 1][(wv * 528 + 5 * 64) * 8]);    \
        GLD(Pbyte + so[6] + ko, &Ss[((KC) + 1) & 1][(wv * 528 + 6 * 64) * 8]);    \
        GLD(Pbyte + so[7] + ko, &Ss[((KC) + 1) & 1][(wv * 528 + 7 * 64) * 8]);    \
        GLD(Pbyte + so[8] + ko, &Ss[((KC) + 1) & 1][(wv * 528 + 8 * 64) * 8]);    \
    }                                                                             \
    { /* B frags from strip + 32 MFMA */                                          \
        const char* sbase = (const char*)&Ss[SB][0] + (rrw + (DYv)) * 8448;       \
        bf16x8 bv0 = *(const bf16x8*)(sbase + oBt[DXv][0]);                       \
        bf16x8 bv1 = *(const bf16x8*)(sbase + oBt[DXv][1]);                       \
        bf16x8 bv2 = *(const bf16x8*)(sbase + oBt[DXv][2]);                       \
        bf16x8 bv3 = *(const bf16x8*)(sbase + oBt[DXv][3]);                       \
        __builtin_amdgcn_s_setprio(1);                                            \
        acc[0][0]=MFMA_(AC[0],bv0,acc[0][0]); acc[1][0]=MFMA_(AC[1],bv0,acc[1][0]);\
        acc[2][0]=MFMA_(AC[2],bv0,acc[2][0]); acc[3][0]=MFMA_(AC[3],bv0,acc[3][0]);\
        acc[4][0]=MFMA_(AC[4],bv0,acc[4][0]); acc[5][0]=MFMA_(AC[5],bv0,acc[5][0]);\
        acc[6][0]=MFMA_(AC[6],bv0,acc[6][0]); acc[7][0]=MFMA_(AC[7],bv0,acc[7][0]);\
        acc[0][1]=MFMA_(AC[0],bv1,acc[0][1]); acc[1][1]=MFMA_(AC[1],bv1,acc[1][1]);\
        acc[2][1]=MFMA_(AC[2],bv1,acc[2][1]); acc[3][1]=MFMA_(AC[3],bv1,acc[3][1]);\
        acc[4][1]=MFMA_(AC[4],bv1,acc[4][1]); acc[5][1]=MFMA_(AC[5],bv1,acc[5][1]);\
        acc[6][1]=MFMA_(AC[6],bv1,acc[6][1]); acc[7][1]=MFMA_(AC[7],bv1,acc[7][1]);\
        acc[0][2]=MFMA_(AC[0],bv2,acc[0][2]); acc[1][2]=MFMA_(AC[1],bv2,acc[1][2]);\
        acc[2][2]=MFMA_(AC[2],bv2,acc[2][2]); acc[3][2]=MFMA_(AC[3],bv2,acc[3][2]);\
        acc[4][2]=MFMA_(AC[4],bv2,acc[4][2]); acc[5][2]=MFMA_(AC[5],bv2,acc[5][2]);\
        acc[6][2]=MFMA_(AC[6],bv2,acc[6][2]); acc[7][2]=MFMA_(AC[7],bv2,acc[7][2]);\
        acc[0][3]=MFMA_(AC[0],bv3,acc[0][3]); acc[1][3]=MFMA_(AC[1],bv3,acc[1][3]);\
        acc[2][3]=MFMA_(AC[2],bv3,acc[2][3]); acc[3][3]=MFMA_(AC[3],bv3,acc[3][3]);\
        acc[4][3]=MFMA_(AC[4],bv3,acc[4][3]); acc[5][3]=MFMA_(AC[5],bv3,acc[5][3]);\
        acc[6][3]=MFMA_(AC[6],bv3,acc[6][3]); acc[7][3]=MFMA_(AC[7],bv3,acc[7][3]);\
        __builtin_amdgcn_s_setprio(0);                                            \
    }                                                                             \
    if ((J) == 6 && !(LAST_IT)) {                                                 \
        /* next chunk's strip (9, older than the 8 A just issued) must land */    \
        asm volatile("s_waitcnt vmcnt(8)" ::: "memory");                          \
        __builtin_amdgcn_s_barrier();                                             \
    }                                                                             \
}

__global__ __launch_bounds__(256, 2) void conv_strip(
        const bf16* __restrict__ P, const bf16* __restrict__ W2,
        const float* __restrict__ bias, float* __restrict__ out) {
    // 2 strip buffers: 2160 slots x 16B = 34,560 B each (4 rows x 132 cols x 4 kg
    // = 2112 real slots + 48 slack for the uniform 9-GLD/wave coverage)
    __shared__ __align__(16) bf16 Ss[2][17280];

    const int bid = blockIdx.x;
    const int w   = (bid & 7) * 240 + (bid >> 3);   // XCD swizzle, 1920 = 8*240
    const int mblk  = w % 3;
    const int ntile = (w / 3) % 32;
    const int bc    = w / 96;
    const int c = bc % 5, b = bc / 5;
    const int y0 = ntile * 2;

    const int tid  = threadIdx.x;
    const int lane = tid & 63;
    const int wv   = tid >> 6;          // 0..3
    const int lm   = lane & 15, lg = lane >> 4;
    const int rrw  = wv >> 1;           // wave's output row within tile (0/1)

    const bf16* Pslice = P + (size_t)(b * 5 + c) * PSZ * KD;
    const char* Pbyte  = (const char*)Pslice;

    // A per-lane base: row = mblk*128 + i*16 + lm, k = 8*lg  (same map as R2)
    const bf16* gAbase = W2 + (size_t)(mblk * 128 + lm) * KD + 8 * lg;

    // strip staging source byte-offsets (9 rounds/wave); slot s -> (r,cc,kg),
    // layout [4 rows][132 cols][4 kg]; junk slots clamped to safe duplicates
    unsigned so[9];
    #pragma unroll
    for (int r9 = 0; r9 < 9; ++r9) {
        int s  = wv * 528 + r9 * 64 + lane;
        int r  = (s / 528) & 3;                      // slack slots wrap to row 0
        int cc = (s % 528) >> 2;
        if (cc >= 130) cc &= 127;                    // junk cols -> safe dupes
        int kg = s & 3;
        so[r9] = (unsigned)((((y0 + r) * PW + cc) * KD + 8 * (kg ^ ((cc >> 1) & 3))) * 2);
    }

    // B ds-read byte offsets (col+kg part); row part added per tap (dy)
    int oBt[3][4];
    #pragma unroll
    for (int dx = 0; dx < 3; ++dx)
        #pragma unroll
        for (int j4 = 0; j4 < 4; ++j4) {
            int cc = dx + (wv & 1) * 64 + j4 * 16 + lm;
            oBt[dx][j4] = (cc * 4 + (lg ^ ((cc >> 1) & 3))) * 16;
        }

    f32x4 acc[8][4] = {};
    bf16x8 aA[8], aB[8];

    // ---- prologue: stage strip(0), then load A(kc=0, tap 0) into aA
    #pragma unroll
    for (int r9 = 0; r9 < 9; ++r9)
        GLD(Pbyte + so[r9], &Ss[0][(wv * 528 + r9 * 64) * 8]);
    #pragma unroll
    for (int i = 0; i < 8; ++i)
        aA[i] = *(const bf16x8*)(gAbase + (size_t)i * (16 * KD));
    asm volatile("s_waitcnt vmcnt(8)" ::: "memory");   // strip(0) (oldest 9) landed
    __builtin_amdgcn_s_barrier();

    #pragma unroll 1
    for (int kc2 = 0; kc2 < 6; ++kc2) {
        const int kcA = kc2 * 2;
        const int kcB = kcA + 1;
        const bool last = (kc2 == 5);
        // chunk kcA (even -> strip buf 0); A parity: cur aA at j=0
        BODY(kcA, 0, 0, 0, 0, aA, aB, false)
        BODY(kcA, 1, 0, 1, 0, aB, aA, false)
        BODY(kcA, 2, 1, 0, 0, aA, aB, false)
        BODY(kcA, 3, 1, 1, 0, aB, aA, false)
        BODY(kcA, 4, 1, 2, 0, aA, aB, false)
        BODY(kcA, 5, 2, 1, 0, aB, aA, false)
        BODY(kcA, 6, 2, 2, 0, aA, aB, false)
        // chunk kcB (odd -> strip buf 1); cur aB at j=0
        BODY(kcB, 0, 0, 0, 1, aB, aA, false)
        BODY(kcB, 1, 0, 1, 1, aA, aB, false)
        BODY(kcB, 2, 1, 0, 1, aB, aA, false)
        BODY(kcB, 3, 1, 1, 1, aA, aB, false)
        BODY(kcB, 4, 1, 2, 1, aB, aA, false)
        BODY(kcB, 5, 2, 1, 1, aA, aB, false)
        BODY(kcB, 6, 2, 2, 1, aB, aA, last)
    }

    // epilogue: bias + VMASK + store (unchanged from R8)
    const int m0 = mblk * 128;
    const int yq = y0 + rrw;
    const int xb = (wv & 1) * 64;
    #pragma unroll
    for (int i = 0; i < 8; ++i) {
        #pragma unroll
        for (int r = 0; r < 4; ++r) {
            int m = m0 + i * 16 + lg * 4 + r;
            float bv = bias[m / 6];
            #pragma unroll
            for (int j = 0; j < 4; ++j) {
                int xq = xb + j * 16 + lm;
                float v = acc[i][j][r] + bv;
                if ((yq == 0 && xq == 127) || (yq == 63 && xq == 0)) v = 0.f;
                out[((size_t)(b * MD + m) * CH_ + c) * (HH * WW_) + yq * WW_ + xq] = v;
            }
        }
    }
}

extern "C" void kernel_launch(void* const* d_in, const int* in_sizes, int n_in,
                              void* d_out, int out_size, void* d_ws, size_t ws_size,
                              hipStream_t stream) {
    const float* x    = (const float*)d_in[0];
    const float* w    = (const float*)d_in[1];
    const float* bias = (const float*)d_in[2];
    float* out        = (float*)d_out;

    bf16* W2 = (bf16*)d_ws;
    bf16* P  = (bf16*)((char*)d_ws + WEXP2_BYTES);

    wexp2_kernel<<<(WEXP2_ELEMS + 255) / 256, 256, 0, stream>>>(w, W2);
    pad_interior<<<20 * 64 * 2 * 3, 256, 0, stream>>>(x, P);
    pad_border<<<(20 * NBORD * KD + 255) / 256, 256, 0, stream>>>(x, P);

    // grid: 3 m-blocks x 32 n-tiles x 20 (b,c) = 1920 blocks, 256 threads
    conv_strip<<<1920, 256, 0, stream>>>(P, W2, bias, out);
}

// Round 12
// 480.165 us; speedup vs baseline: 2.6742x; 2.6742x over previous
//
#include <hip/hip_runtime.h>
#include <hip/hip_bf16.h>

// Problem constants
#define BB    4
#define CIN_  64
#define RIN_  6
#define CH_   5
#define HH    64
#define WW_   128
#define KD    384
#define MD    384
#define PH    66
#define PW    130
#define PSZ   (PH*PW)

#define NTAP 7
#define WEXP2_ELEMS (NTAP*MD*KD)
#define WEXP2_BYTES (WEXP2_ELEMS*2)

// fused prep grid layout
#define NB_INTERIOR 7680                 // 20 bc x 64 y x 2 xh x 3 kblk
#define NB_BORDER   380                  // 20 bc x 19 (4656 idx / 256)
#define NB_WEXP     4032                 // 1,032,192 / 256
#define NB_PREP     (NB_INTERIOR + NB_BORDER + NB_WEXP)

typedef __hip_bfloat16 bf16;
typedef __attribute__((ext_vector_type(8))) short bf16x8;
typedef __attribute__((ext_vector_type(4))) float f32x4;

__device__ const int TMAP[NTAP] = {0,1,3,4,5,7,8};
__device__ const int IDXK[6][9] = {
    {5,4,6,6,0,3,6,1,2},
    {4,3,6,5,0,2,6,6,1},
    {3,2,6,4,0,1,6,5,6},
    {2,1,6,3,0,6,6,4,5},
    {1,6,6,2,0,5,6,3,4},
    {6,5,6,1,0,4,6,2,3},
};

// -------- fused prep kernel: interior pad + border gather + weight expand
__global__ __launch_bounds__(256) void prep_kernel(const float* __restrict__ x,
                                                   const float* __restrict__ w,
                                                   bf16* __restrict__ P,
                                                   bf16* __restrict__ W2) {
    const int blk = blockIdx.x;
    const int tid = threadIdx.x;

    if (blk < NB_INTERIOR) {
        // ---- interior pad (transpose to channel-last), unchanged logic
        int bid  = blk;
        int kblk = bid % 3;
        int xh   = (bid / 3) & 1;
        int y    = (bid / 6) % 64;
        int bc   = bid / 384;
        int c = bc % 5, b = bc / 5;

        int lane = tid & 63;
        int wv   = tid >> 6;
        int k0   = kblk * 128 + wv * 32;
        int sx   = xh * 64 + lane;
        int xx   = sx + 1;

        bool mask0 = (y == 0 && sx == 127) || (y == 63 && sx == 0);

        const float* src = x + ((((size_t)(b * 384 + k0) * 5 + c) * 64 + y) * 128 + sx);
        unsigned int hbuf[16];
        #pragma unroll
        for (int kk = 0; kk < 32; kk += 2) {
            float v1 = src[(size_t)kk * 40960];
            float v2 = src[(size_t)(kk + 1) * 40960];
            if (mask0) { v1 = 0.f; v2 = 0.f; }
            bf16 h1 = __float2bfloat16(v1);
            bf16 h2 = __float2bfloat16(v2);
            hbuf[kk >> 1] = ((unsigned int)*(unsigned short*)&h2 << 16) |
                            (unsigned int)*(unsigned short*)&h1;
        }
        bf16* dst = P + (((size_t)(b * 5 + c) * PH + (y + 1)) * PW + xx) * KD + k0;
        uint4* d4 = (uint4*)dst;
        #pragma unroll
        for (int q = 0; q < 4; ++q)
            d4[q] = make_uint4(hbuf[4*q], hbuf[4*q+1], hbuf[4*q+2], hbuf[4*q+3]);
        return;
    }

    if (blk < NB_INTERIOR + NB_BORDER) {
        // ---- border gather: thread = (cell p, k-chunk of 32)
        // per-p params hoisted (same branch table as the verified scalar kernel);
        // inner loop walks 32 k with lane-adjacent p -> coalesced x reads.
        int bidB = blk - NB_INTERIOR;
        int bc   = bidB / 19;
        int idx  = (bidB % 19) * 256 + tid;
        if (idx >= 12 * 388) return;
        int c = bc % 5, b = bc / 5;
        int chunk = idx / 388;          // 0..11 (32 k each)
        int p     = idx % 388;

        int yy, xx;
        if (p < 130)      { yy = 0;  xx = p; }
        else if (p < 260) { yy = 65; xx = p - 130; }
        else if (p < 324) { yy = 1 + (p - 260); xx = 0; }
        else              { yy = 1 + (p - 324); xx = 129; }

        // hoisted gather params: sr = zi ? 0 : (r + dr) % 6
        int dr = 0, sc = c, sy = 0, sx = 0;
        bool zi = false;
        if (xx == 129) {
            if (yy >= 2) { dr = 5; sc = (c + 1) % 5; sy = 0; sx = 129 - yy; }
            else zi = true;
        } else if (yy == 0) {
            if (xx >= 1 && xx <= 64)        { dr = 0; sc = (c + 4) % 5; sy = 63; sx = 63 + xx; }
            else if (xx >= 65 && xx <= 128) { dr = 1; sc = (c + 4) % 5; sy = 128 - xx; sx = 127; }
            else zi = true;
        } else if (yy == 65) {
            if (xx >= 65 && xx <= 128)      { dr = 0; sc = (c + 1) % 5; sy = 0; sx = xx - 65; }
            else if (xx >= 2 && xx <= 64)   { dr = 1; sc = (c + 1) % 5; sy = 65 - xx; sx = 0; }
            else zi = true;
        } else { // xx==0, yy in [1,64]
            dr = 5; sc = (c + 4) % 5; sy = 63; sx = 64 - yy;
        }
        if (zi) { dr = 0; sc = 0; sy = 0; sx = 0; }
        bool kill = !zi && ((sy == 0 && sx == 127) || (sy == 63 && sx == 0));

        // addr = SBASE + (ci*6+sr)*40960
        const size_t SBASE = ((size_t)(b * 1920 + sc)) * 8192 + sy * 128 + sx;
        const int k0 = chunk * 32;

        unsigned int hb[16];
        #pragma unroll
        for (int kk = 0; kk < 32; ++kk) {
            int k  = k0 + kk;
            int ci = k / 6;
            int r  = k - 6 * ci;
            int sr = zi ? 0 : ((r + dr >= 6) ? r + dr - 6 : r + dr);
            float v = x[SBASE + (size_t)(ci * 6 + sr) * 40960];
            if (kill) v = 0.f;
            bf16 h = __float2bfloat16(v);
            unsigned int hu = (unsigned int)*(unsigned short*)&h;
            if (kk & 1) hb[kk >> 1] |= hu << 16;
            else        hb[kk >> 1]  = hu;
        }
        bf16* dst = P + (((size_t)(b * 5 + c) * PH + yy) * PW + xx) * KD + k0;
        uint4* d4 = (uint4*)dst;
        #pragma unroll
        for (int q = 0; q < 4; ++q)
            d4[q] = make_uint4(hb[4*q], hb[4*q+1], hb[4*q+2], hb[4*q+3]);
        return;
    }

    // ---- weight expand -> W2 bf16 [tt=7][m=384][k=384]
    {
        int e = (blk - NB_INTERIOR - NB_BORDER) * 256 + tid;
        if (e >= WEXP2_ELEMS) return;
        int k  = e % KD;
        int m  = (e / KD) % MD;
        int tt = e / (KD * MD);
        int t  = TMAP[tt];
        int co = m / 6, ro = m % 6, ci = k / 6, ri = k % 6;
        int rw = (ri - ro + 6) % 6;
        int s  = IDXK[ro][t];
        W2[e] = __float2bfloat16(w[((co * CIN_ + ci) * RIN_ + rw) * 7 + s]);
    }
}

// -------- conv kernel: byte-identical to Round 8 (best verified: 386 us, 876 TF-eq)
// 4 waves/block (256 thr); wave-tile 128m x 64n (acc 8x4 frags)
// BM=128, BN=256 (2 y-rows x 128 x), BK=32; 84 K-tiles = 7 taps x 12 chunks
// LDS: 3 buffers (stage t+2 while computing t); vmcnt(6) steady state.
#define DYP 0x2950   // packed dy per tap: 0,0,1,1,1,2,2
#define DXP 0x2644   // packed dx per tap: 0,1,0,1,2,1,2

#define GLD(g, l) __builtin_amdgcn_global_load_lds( \
    (const __attribute__((address_space(1))) void*)(g), \
    (__attribute__((address_space(3))) void*)(l), 16, 0, 0)
#define MFMA_(a, b, c) __builtin_amdgcn_mfma_f32_16x16x32_bf16((a), (b), (c), 0, 0, 0)

__global__ __launch_bounds__(256, 2) void conv_mfma4(
        const bf16* __restrict__ P, const bf16* __restrict__ W2,
        const float* __restrict__ bias, float* __restrict__ out) {
    __shared__ __align__(16) bf16 As[3][4096];   // 128 m x 32 k per buf (8 KB)
    __shared__ __align__(16) bf16 Bs[3][8192];   // 256 n x 32 k per buf (16 KB)

    const int bid = blockIdx.x;
    const int w   = (bid & 7) * 240 + (bid >> 3);   // XCD swizzle, 1920 = 8*240
    const int mblk  = w % 3;
    const int ntile = (w / 3) % 32;
    const int bc    = w / 96;
    const int c = bc % 5, b = bc / 5;
    const int y0 = ntile * 2;

    const int tid  = threadIdx.x;
    const int lane = tid & 63;
    const int wv   = tid >> 6;          // 0..3
    const int lm   = lane & 15, lg = lane >> 4;

    const bf16* Pslice = P + (size_t)(b * 5 + c) * PSZ * KD;

    // ds-read byte offsets (swizzled): slot = idx*4 + (lg ^ ((idx>>1)&3)), 16 B/slot
    int oA[8], oB[4];
    #pragma unroll
    for (int i = 0; i < 8; ++i) {
        int mm = i * 16 + lm;
        oA[i] = (mm * 4 + (lg ^ ((mm >> 1) & 3))) * 16;
    }
    #pragma unroll
    for (int j = 0; j < 4; ++j) {
        int nn = wv * 64 + j * 16 + lm;
        oB[j] = (nn * 4 + (lg ^ ((nn >> 1) & 3))) * 16;
    }
    const char* Ab = (const char*)&As[0][0];
    const char* Bb = (const char*)&Bs[0][0];

    // staging thread-constant base pointers (pre-swizzled global source)
    const bf16* gA[2];
    #pragma unroll
    for (int q = 0; q < 2; ++q) {
        int s = wv * 128 + q * 64 + lane;
        int row = s >> 2, j = s & 3;
        gA[q] = W2 + (size_t)(mblk * 128 + row) * KD + ((j ^ ((row >> 1) & 3)) << 3);
    }
    // B: LDS col n -> padded image row (y0+dy) + (n>>7), x = dx + (n&127):
    // fold the row split into the base: ncol = (col&127) + (col>>7)*PW.
    const bf16* gB[4];
    #pragma unroll
    for (int q = 0; q < 4; ++q) {
        int s = wv * 256 + q * 64 + lane;
        int col = s >> 2, j = s & 3;
        int ncol = (col & 127) + (col >> 7) * PW;
        gB[q] = Pslice + (size_t)ncol * KD + ((j ^ ((col >> 1) & 3)) << 3);
    }

    f32x4 acc[8][4] = {};

    // prologue: stage tile 0 -> buf0, tile 1 -> buf1 (tap 0: dy=0, dx=0)
    #pragma unroll
    for (int t = 0; t < 2; ++t) {
        size_t offA = (size_t)t * 32;
        size_t offB = (size_t)y0 * PW * KD + t * 32;
        GLD(gA[0] + offA, &As[t][(wv * 128) * 8]);
        GLD(gA[1] + offA, &As[t][(wv * 128 + 64) * 8]);
        #pragma unroll
        for (int q = 0; q < 4; ++q)
            GLD(gB[q] + offB, &Bs[t][(wv * 256 + q * 64) * 8]);
    }
    asm volatile("s_waitcnt vmcnt(6)" ::: "memory");   // tile 0 landed (this wave)
    __builtin_amdgcn_s_barrier();                      // => all waves' tile 0 landed

    #pragma unroll 1
    for (int tt = 0; tt < 7; ++tt) {
        #pragma unroll
        for (int kc = 0; kc < 12; ++kc) {
            const int rb   = kc % 3;            // read buffer (static; 12*tt % 3 == 0)
            const int sb   = (kc + 2) % 3;      // stage buffer (static)
            const int skc  = (kc + 2) % 12;     // staged tile k-chunk (static)
            const int stt  = tt + (kc + 2) / 12;
            const bool dostage = (stt < 7);
            const bool drain   = (tt == 6 && kc >= 10);

            // ---- ds_read all 12 fragments of current chunk (from rb)
            bf16x8 a0 = *(const bf16x8*)(Ab + rb * 8192 + oA[0]);
            bf16x8 a1 = *(const bf16x8*)(Ab + rb * 8192 + oA[1]);
            bf16x8 a2 = *(const bf16x8*)(Ab + rb * 8192 + oA[2]);
            bf16x8 a3 = *(const bf16x8*)(Ab + rb * 8192 + oA[3]);
            bf16x8 a4 = *(const bf16x8*)(Ab + rb * 8192 + oA[4]);
            bf16x8 a5 = *(const bf16x8*)(Ab + rb * 8192 + oA[5]);
            bf16x8 a6 = *(const bf16x8*)(Ab + rb * 8192 + oA[6]);
            bf16x8 a7 = *(const bf16x8*)(Ab + rb * 8192 + oA[7]);
            bf16x8 b0 = *(const bf16x8*)(Bb + rb * 16384 + oB[0]);
            bf16x8 b1 = *(const bf16x8*)(Bb + rb * 16384 + oB[1]);
            bf16x8 b2 = *(const bf16x8*)(Bb + rb * 16384 + oB[2]);
            bf16x8 b3 = *(const bf16x8*)(Bb + rb * 16384 + oB[3]);

            // ---- stage tile t+2 (6 loads/wave) into sb
            if (dostage) {
                const int dy = (DYP >> (2 * stt)) & 3;
                const int dx = (DXP >> (2 * stt)) & 3;
                size_t offA = (size_t)stt * (MD * KD) + skc * 32;
                size_t offB = ((size_t)(y0 + dy) * PW + dx) * KD + skc * 32;
                GLD(gA[0] + offA, &As[sb][(wv * 128) * 8]);
                GLD(gA[1] + offA, &As[sb][(wv * 128 + 64) * 8]);
                GLD(gB[0] + offB, &Bs[sb][(wv * 256) * 8]);
                GLD(gB[1] + offB, &Bs[sb][(wv * 256 + 64) * 8]);
                GLD(gB[2] + offB, &Bs[sb][(wv * 256 + 128) * 8]);
                GLD(gB[3] + offB, &Bs[sb][(wv * 256 + 192) * 8]);
            }

            // ---- 32 MFMA; compiler inserts counted lgkmcnt before first uses
            __builtin_amdgcn_s_setprio(1);
            acc[0][0] = MFMA_(a0, b0, acc[0][0]);
            acc[1][0] = MFMA_(a1, b0, acc[1][0]);
            acc[2][0] = MFMA_(a2, b0, acc[2][0]);
            acc[3][0] = MFMA_(a3, b0, acc[3][0]);
            acc[4][0] = MFMA_(a4, b0, acc[4][0]);
            acc[5][0] = MFMA_(a5, b0, acc[5][0]);
            acc[6][0] = MFMA_(a6, b0, acc[6][0]);
            acc[7][0] = MFMA_(a7, b0, acc[7][0]);
            acc[0][1] = MFMA_(a0, b1, acc[0][1]);
            acc[1][1] = MFMA_(a1, b1, acc[1][1]);
            acc[2][1] = MFMA_(a2, b1, acc[2][1]);
            acc[3][1] = MFMA_(a3, b1, acc[3][1]);
            acc[4][1] = MFMA_(a4, b1, acc[4][1]);
            acc[5][1] = MFMA_(a5, b1, acc[5][1]);
            acc[6][1] = MFMA_(a6, b1, acc[6][1]);
            acc[7][1] = MFMA_(a7, b1, acc[7][1]);
            acc[0][2] = MFMA_(a0, b2, acc[0][2]);
            acc[1][2] = MFMA_(a1, b2, acc[1][2]);
            acc[2][2] = MFMA_(a2, b2, acc[2][2]);
            acc[3][2] = MFMA_(a3, b2, acc[3][2]);
            acc[4][2] = MFMA_(a4, b2, acc[4][2]);
            acc[5][2] = MFMA_(a5, b2, acc[5][2]);
            acc[6][2] = MFMA_(a6, b2, acc[6][2]);
            acc[7][2] = MFMA_(a7, b2, acc[7][2]);
            acc[0][3] = MFMA_(a0, b3, acc[0][3]);
            acc[1][3] = MFMA_(a1, b3, acc[1][3]);
            acc[2][3] = MFMA_(a2, b3, acc[2][3]);
            acc[3][3] = MFMA_(a3, b3, acc[3][3]);
            acc[4][3] = MFMA_(a4, b3, acc[4][3]);
            acc[5][3] = MFMA_(a5, b3, acc[5][3]);
            acc[6][3] = MFMA_(a6, b3, acc[6][3]);
            acc[7][3] = MFMA_(a7, b3, acc[7][3]);
            __builtin_amdgcn_s_setprio(0);

            // ---- end-of-chunk: tile t+1 landed (this wave), then block-wide sync
            if (drain) {
                asm volatile("s_waitcnt vmcnt(0)" ::: "memory");
            } else {
                asm volatile("s_waitcnt vmcnt(6)" ::: "memory");
            }
            __builtin_amdgcn_s_barrier();
        }
    }

    // epilogue: bias + VMASK + store
    const int m0 = mblk * 128;
    const int yq = y0 + (wv >> 1);
    const int xb = (wv & 1) * 64;
    #pragma unroll
    for (int i = 0; i < 8; ++i) {
        #pragma unroll
        for (int r = 0; r < 4; ++r) {
            int m = m0 + i * 16 + lg * 4 + r;
            float bv = bias[m / 6];
            #pragma unroll
            for (int j = 0; j < 4; ++j) {
                int xq = xb + j * 16 + lm;
                float v = acc[i][j][r] + bv;
                if ((yq == 0 && xq == 127) || (yq == 63 && xq == 0)) v = 0.f;
                out[((size_t)(b * MD + m) * CH_ + c) * (HH * WW_) + yq * WW_ + xq] = v;
            }
        }
    }
}

extern "C" void kernel_launch(void* const* d_in, const int* in_sizes, int n_in,
                              void* d_out, int out_size, void* d_ws, size_t ws_size,
                              hipStream_t stream) {
    const float* x    = (const float*)d_in[0];
    const float* w    = (const float*)d_in[1];
    const float* bias = (const float*)d_in[2];
    float* out        = (float*)d_out;

    bf16* W2 = (bf16*)d_ws;
    bf16* P  = (bf16*)((char*)d_ws + WEXP2_BYTES);

    // one fused prep launch: interior pad + border gather + weight expand
    prep_kernel<<<NB_PREP, 256, 0, stream>>>(x, w, P, W2);

    // grid: 3 m-blocks x 32 n-tiles x 20 (b,c) = 1920 blocks, 256 threads
    conv_mfma4<<<1920, 256, 0, stream>>>(P, W2, bias, out);
}